// Round 9
// baseline (377.084 us; speedup 1.0000x reference)
//
#include <hip/hip_runtime.h>

typedef short bf16x8 __attribute__((ext_vector_type(8)));
typedef float f32x4 __attribute__((ext_vector_type(4)));

__device__ __forceinline__ float b2f(unsigned short u) {
  union { unsigned int i; float f; } v; v.i = ((unsigned int)u) << 16; return v.f;
}
__device__ __forceinline__ unsigned short f2b(float f) {
  unsigned int u = __float_as_uint(f);
  u += 0x7fffu + ((u >> 16) & 1u);
  return (unsigned short)(u >> 16);
}
__device__ __forceinline__ float silu_f(float s) { return s / (1.0f + __expf(-s)); }

// split fp32 -> (hi, lo) bf16
__device__ __forceinline__ void split2(float f, unsigned short& h, unsigned short& l) {
  h = f2b(f);
  l = f2b(f - b2f(h));
}

// async 16B/lane global->LDS. LDS dest = wave-uniform base + lane*16 (linear).
__device__ __forceinline__ void gload16(const unsigned short* g, unsigned short* l) {
  __builtin_amdgcn_global_load_lds(
      (const __attribute__((address_space(1))) unsigned int*)g,
      (__attribute__((address_space(3))) unsigned int*)l, 16, 0, 0);
}

// unpack 8 packed (hi | lo<<16) u32 -> hi/lo bf16x8 via v_perm (2 ops per pair)
__device__ __forceinline__ void unpack8(const unsigned* p, bf16x8& hi, bf16x8& lo) {
  uint4 a = *(const uint4*)p;
  uint4 b = *(const uint4*)(p + 4);
  unsigned u[8] = {a.x, a.y, a.z, a.w, b.x, b.y, b.z, b.w};
  unsigned hw[4], lw[4];
  #pragma unroll
  for (int j = 0; j < 4; j++) {
    hw[j] = __builtin_amdgcn_perm(u[2 * j + 1], u[2 * j], 0x05040100u);
    lw[j] = __builtin_amdgcn_perm(u[2 * j + 1], u[2 * j], 0x07060302u);
  }
  hi = *(bf16x8*)hw;
  lo = *(bf16x8*)lw;
}

// K1 (fused): blocks 0..63: W rows 0..511 (q,k) fp32 -> row-major Wh/Wl planes.
// blocks 64..: prep: x_preact = silu(x+pab) fp32 -> out[:,0:256];
//   T = x_preact + pqb TRANSPOSED split planes -> Tn (ws): per b {Th,Tl} u16[4096][256]
//   (u32-granular XOR-swizzled LDS transpose: bank-conflict-free)
__global__ __launch_bounds__(256) void k_prep(
    const float* __restrict__ x, const float* __restrict__ pab,
    const float* __restrict__ pqb, const float* __restrict__ W,
    unsigned short* __restrict__ Wh, unsigned short* __restrict__ Wl,
    unsigned short* __restrict__ Tn, float* __restrict__ out) {
  __shared__ unsigned th2[64 * 32], tl2[64 * 32];  // u32 [n][cpair], XOR-swizzled
  int blk = blockIdx.x;
  if (blk < 64) {  // ---- W split (rows 0..511 only; v rows not needed) ----
    int e = (blk * 256 + threadIdx.x) * 8;  // 0..131071
    float4 a = *(const float4*)(W + e);
    float4 bq = *(const float4*)(W + e + 4);
    float v[8] = {a.x, a.y, a.z, a.w, bq.x, bq.y, bq.z, bq.w};
    unsigned short h8[8], l8[8];
    #pragma unroll
    for (int j = 0; j < 8; j++) split2(v[j], h8[j], l8[j]);
    uint4 ph, pl;
    ph.x = h8[0] | ((unsigned)h8[1] << 16); ph.y = h8[2] | ((unsigned)h8[3] << 16);
    ph.z = h8[4] | ((unsigned)h8[5] << 16); ph.w = h8[6] | ((unsigned)h8[7] << 16);
    pl.x = l8[0] | ((unsigned)l8[1] << 16); pl.y = l8[2] | ((unsigned)l8[3] << 16);
    pl.z = l8[4] | ((unsigned)l8[5] << 16); pl.w = l8[6] | ((unsigned)l8[7] << 16);
    *(uint4*)(Wh + e) = ph;
    *(uint4*)(Wl + e) = pl;
    return;
  }
  blk -= 64;  // ---- prep ----
  int nb = blk & 63;
  int cb = (blk >> 6) & 3;
  int b = blk >> 8;
  int n0 = nb * 64, c0 = cb * 64;
  int t = threadIdx.x;
  int nn = (t & 15) * 4;
  #pragma unroll
  for (int p = 0; p < 2; p++) {
    int cp = p * 16 + (t >> 4);  // channel pair index within 64-c tile
    int c = 2 * cp;
    float pa0 = pab[c0 + c], pq0 = pqb[c0 + c];
    float pa1 = pab[c0 + c + 1], pq1 = pqb[c0 + c + 1];
    float4 x0 = *(const float4*)(x + ((long long)(b * 256 + c0 + c)) * 4096 + n0 + nn);
    float4 x1 = *(const float4*)(x + ((long long)(b * 256 + c0 + c + 1)) * 4096 + n0 + nn);
    float s0[4] = {silu_f(x0.x + pa0), silu_f(x0.y + pa0),
                   silu_f(x0.z + pa0), silu_f(x0.w + pa0)};
    float s1[4] = {silu_f(x1.x + pa1), silu_f(x1.y + pa1),
                   silu_f(x1.z + pa1), silu_f(x1.w + pa1)};
    float4 sv0 = {s0[0], s0[1], s0[2], s0[3]};
    float4 sv1 = {s1[0], s1[1], s1[2], s1[3]};
    *(float4*)(out + ((long long)(b * 512 + c0 + c)) * 4096 + n0 + nn) = sv0;
    *(float4*)(out + ((long long)(b * 512 + c0 + c + 1)) * 4096 + n0 + nn) = sv1;
    float t0[4] = {s0[0] + pq0, s0[1] + pq0, s0[2] + pq0, s0[3] + pq0};
    float t1[4] = {s1[0] + pq1, s1[1] + pq1, s1[2] + pq1, s1[3] + pq1};
    #pragma unroll
    for (int j = 0; j < 4; j++) {
      int nr = nn + j;
      unsigned short h0, l0, h1, l1;
      split2(t0[j], h0, l0);
      split2(t1[j], h1, l1);
      int pidx = nr * 32 + (cp ^ (nr & 31));  // u32 XOR swizzle: ~2-way banks
      th2[pidx] = (unsigned)h0 | ((unsigned)h1 << 16);
      tl2[pidx] = (unsigned)l0 | ((unsigned)l1 << 16);
    }
  }
  __syncthreads();
  unsigned short* Th = Tn + (long long)b * 2097152;
  unsigned short* Tl = Th + 1048576;
  #pragma unroll
  for (int q = 0; q < 2; q++) {
    int s = q * 256 + t;
    int n = s >> 3, sc = s & 7;
    unsigned wh[4], wl[4];
    #pragma unroll
    for (int j = 0; j < 4; j++) {
      int pidx = n * 32 + ((sc * 4 + j) ^ (n & 31));
      wh[j] = th2[pidx];
      wl[j] = tl2[pidx];
    }
    uint4 vh = {wh[0], wh[1], wh[2], wh[3]};
    uint4 vl = {wl[0], wl[1], wl[2], wl[3]};
    *(uint4*)(Th + (long long)(n0 + n) * 256 + c0 + sc * 8) = vh;
    *(uint4*)(Tl + (long long)(n0 + n) * 256 + c0 + sc * 8) = vl;
  }
}

// K2: fused q/k GEMM + logits (v REMOVED - handled algebraically downstream).
// One block = (b, head, ntile of 128 n). R7 staging structure (proven fastest),
// 24 chunks (6/wave): Ah(q,k) Al(q,k) Bh Bl. 3-term split-bf16, bit-identical
// q,k,logits to prior rounds. qk tile stride 132 u32 + red stride 33 (R8 bank fix).
__global__ __launch_bounds__(256, 3) void k_qkl(
    const unsigned short* __restrict__ Wh, const unsigned short* __restrict__ Wl,
    const float* __restrict__ qkvb,
    const float* __restrict__ peqh, const float* __restrict__ peqw,
    const float* __restrict__ pekh, const float* __restrict__ pekw,
    const float* __restrict__ modm, const float* __restrict__ modb,
    const unsigned short* __restrict__ Tn, float* __restrict__ logits) {
  __shared__ __align__(16) unsigned char smem[33792];
  unsigned short* stg = (unsigned short*)smem;  // staging: 24KB
  unsigned* qk = (unsigned*)smem;               // 64 x 132 u32 = 33792B
  float* red = (float*)smem;                    // 4 x 1056 f32 = 16896B

  int bx = blockIdx.x;
  int ntile = bx & 31, h = (bx >> 5) & 7, b = bx >> 8;
  int n0 = ntile * 128;
  int t = threadIdx.x, lane = t & 63, w = t >> 6;
  int l15 = lane & 15, l4 = lane >> 4;

  const unsigned short* Thb = Tn + (long long)b * 2097152;
  const unsigned short* Tlb = Thb + 1048576;

  // chunks (16 rows x 32 u16 = 1KB): 0-3 Ah(q,q,k,k), 4-7 Al, 8-15 Bh, 16-23 Bl
  const unsigned short* csrc[6];
  unsigned short* cdst[6];
  int lrow = lane >> 2;
  int lslot = ((lane & 3) ^ ((lane >> 3) & 3)) * 8;  // source-side swizzle
  #pragma unroll
  for (int i = 0; i < 6; i++) {
    int c = w * 6 + i;
    const unsigned short* plane;
    int rowb;
    if (c < 4) {
      plane = Wh; rowb = ((c & 2) ? 256 : 0) + h * 32 + (c & 1) * 16;
    } else if (c < 8) {
      int s2 = c - 4;
      plane = Wl; rowb = ((s2 & 2) ? 256 : 0) + h * 32 + (s2 & 1) * 16;
    } else if (c < 16) {
      plane = Thb; rowb = n0 + (c - 8) * 16;
    } else {
      plane = Tlb; rowb = n0 + (c - 16) * 16;
    }
    csrc[i] = plane + (long long)(rowb + lrow) * 256 + lslot;
    cdst[i] = stg + c * 512;
  }

  int sw = (l4 ^ ((l15 >> 1) & 3)) << 3;  // read-side swizzle
  f32x4 z = {0.f, 0.f, 0.f, 0.f};
  f32x4 acc[4][2];
  #pragma unroll
  for (int i = 0; i < 4; i++)
    #pragma unroll
    for (int j = 0; j < 2; j++) acc[i][j] = z;

  for (int step = 0; step < 8; ++step) {
    int k0 = step * 32;
    #pragma unroll
    for (int i = 0; i < 6; i++) gload16(csrc[i] + k0, cdst[i]);
    __syncthreads();
    bf16x8 ah[4], al[4], bh[2], bl[2];
    #pragma unroll
    for (int i = 0; i < 4; i++) {
      int ro = (i * 16 + l15) * 32 + sw;
      ah[i] = *(const bf16x8*)(stg + ro);
      al[i] = *(const bf16x8*)(stg + 2048 + ro);
    }
    #pragma unroll
    for (int j = 0; j < 2; j++) {
      int ro = (w * 32 + j * 16 + l15) * 32 + sw;
      bh[j] = *(const bf16x8*)(stg + 4096 + ro);
      bl[j] = *(const bf16x8*)(stg + 8192 + ro);
    }
    #pragma unroll
    for (int i = 0; i < 4; i++)
      #pragma unroll
      for (int j = 0; j < 2; j++) {
        acc[i][j] = __builtin_amdgcn_mfma_f32_16x16x32_bf16(ah[i], bh[j], acc[i][j], 0, 0, 0);
        acc[i][j] = __builtin_amdgcn_mfma_f32_16x16x32_bf16(ah[i], bl[j], acc[i][j], 0, 0, 0);
        acc[i][j] = __builtin_amdgcn_mfma_f32_16x16x32_bf16(al[i], bh[j], acc[i][j], 0, 0, 0);
      }
    __syncthreads();
  }

  // q/k epilogue: bias + PE (+FiLM for q), pack, store to qk tile (stride 132)
  int b256 = b * 256;
  #pragma unroll
  for (int i = 0; i < 4; i++) {
    #pragma unroll
    for (int r = 0; r < 4; r++) {
      int row = i * 16 + l4 * 4 + r;  // 0..63; i<2 -> q, i>=2 -> k
      int cch = h * 32 + (row & 31);
      float bias = qkvb[(row & 32) ? (256 + cch) : cch];
      float mm = 0.f, mb = 0.f;
      if (row < 32) { mm = modm[b256 + cch]; mb = modb[b256 + cch]; }
      #pragma unroll
      for (int j = 0; j < 2; j++) {
        int nl = w * 32 + j * 16 + l15;
        int n = n0 + nl;
        int hh = n >> 6, ww = n & 63;
        float v = acc[i][j][r] + bias;
        if (row < 32) {
          v += peqh[cch * 64 + hh] + peqw[cch * 64 + ww];
          v = v * mm + mb;
        } else {
          v += pekh[cch * 64 + hh] + pekw[cch * 64 + ww];
        }
        unsigned short hi_, lo_;
        split2(v, hi_, lo_);
        int pch = (nl >> 3) ^ (row & 15);  // chunk swizzle (8 u32 = 32B chunks)
        qk[row * 132 + pch * 8 + (nl & 7)] = (unsigned)hi_ | ((unsigned)lo_ << 16);
      }
    }
  }
  __syncthreads();

  // logits partial: q(32 x 128n) . k(32 x 128n)^T; wave w covers n-slice w*32..
  f32x4 acc2[2][2] = {z, z, z, z};
  int chn = w * 4 + l4;
  bf16x8 qh[2], ql[2], kh[2], kl[2];
  #pragma unroll
  for (int i2 = 0; i2 < 2; i2++) {
    int row = i2 * 16 + l15;
    unpack8(qk + row * 132 + ((chn ^ l15) << 3), qh[i2], ql[i2]);
    unpack8(qk + (row + 32) * 132 + ((chn ^ l15) << 3), kh[i2], kl[i2]);
  }
  acc2[0][0] = __builtin_amdgcn_mfma_f32_16x16x32_bf16(qh[0], kh[0], acc2[0][0], 0, 0, 0);
  acc2[0][0] = __builtin_amdgcn_mfma_f32_16x16x32_bf16(qh[0], kl[0], acc2[0][0], 0, 0, 0);
  acc2[0][0] = __builtin_amdgcn_mfma_f32_16x16x32_bf16(ql[0], kh[0], acc2[0][0], 0, 0, 0);
  acc2[0][1] = __builtin_amdgcn_mfma_f32_16x16x32_bf16(qh[0], kh[1], acc2[0][1], 0, 0, 0);
  acc2[0][1] = __builtin_amdgcn_mfma_f32_16x16x32_bf16(qh[0], kl[1], acc2[0][1], 0, 0, 0);
  acc2[0][1] = __builtin_amdgcn_mfma_f32_16x16x32_bf16(ql[0], kh[1], acc2[0][1], 0, 0, 0);
  acc2[1][0] = __builtin_amdgcn_mfma_f32_16x16x32_bf16(qh[1], kh[0], acc2[1][0], 0, 0, 0);
  acc2[1][0] = __builtin_amdgcn_mfma_f32_16x16x32_bf16(qh[1], kl[0], acc2[1][0], 0, 0, 0);
  acc2[1][0] = __builtin_amdgcn_mfma_f32_16x16x32_bf16(ql[1], kh[0], acc2[1][0], 0, 0, 0);
  acc2[1][1] = __builtin_amdgcn_mfma_f32_16x16x32_bf16(qh[1], kh[1], acc2[1][1], 0, 0, 0);
  acc2[1][1] = __builtin_amdgcn_mfma_f32_16x16x32_bf16(qh[1], kl[1], acc2[1][1], 0, 0, 0);
  acc2[1][1] = __builtin_amdgcn_mfma_f32_16x16x32_bf16(ql[1], kh[1], acc2[1][1], 0, 0, 0);

  // red aliases qk: wait for ALL waves' qk reads before overwriting
  __syncthreads();
  #pragma unroll
  for (int i2 = 0; i2 < 2; i2++)
    #pragma unroll
    for (int j2 = 0; j2 < 2; j2++)
      #pragma unroll
      for (int r = 0; r < 4; r++)
        red[w * 1056 + (i2 * 16 + l4 * 4 + r) * 33 + j2 * 16 + l15] = acc2[i2][j2][r];
  __syncthreads();
  const float scale = 0.1767766952966369f;  // 1/sqrt(32)
  int bhid = b * 8 + h;
  #pragma unroll
  for (int i = 0; i < 4; i++) {
    int idx = i * 256 + t;
    int crow = idx >> 5, dcol = idx & 31;
    int ro = crow * 33 + dcol;
    float s = (red[ro] + red[1056 + ro] + red[2112 + ro] + red[3168 + ro]) * scale;
    atomicAdd(logits + (long long)bhid * 1024 + idx, s);
  }
}

// K3: per (b,h): softmax(logits) -> weights; E = weights . Wv_h (bf16-hi plane);
// bE = weights . bv written OVER this block's consumed logits[bh][0:32] slots.
__global__ __launch_bounds__(256) void k_corr(
    float* __restrict__ logits, const float* __restrict__ W,
    const float* __restrict__ qkvb, unsigned short* __restrict__ Eh) {
  int bx = blockIdx.x;  // 0..127
  int b = bx >> 3, h = bx & 7;
  int t = threadIdx.x;
  __shared__ float raw[32][33];
  __shared__ float wsm[32][33];
  long long lbase = (long long)bx * 1024;
  #pragma unroll
  for (int i = 0; i < 4; i++) {
    int idx = i * 256 + t;
    raw[idx >> 5][idx & 31] = logits[lbase + idx];
  }
  __syncthreads();
  if (t < 32) {
    float mx = -1e30f;
    for (int d = 0; d < 32; d++) mx = fmaxf(mx, raw[t][d]);
    float e[32]; float s = 0.f;
    for (int d = 0; d < 32; d++) { e[d] = __expf(raw[t][d] - mx); s += e[d]; }
    float inv = 1.0f / s;
    for (int d = 0; d < 32; d++) wsm[t][d] = e[d] * inv;
  }
  __syncthreads();
  if (t < 32) {  // bE -> overlay (raw fully consumed into LDS)
    float s = 0.f;
    for (int d = 0; d < 32; d++) s += wsm[t][d] * qkvb[512 + h * 32 + d];
    logits[lbase + t] = s;
  }
  // E[r][e] = sum_s w[r][s] * Wv[512+h*32+s][e]; thread: r = t>>3, e0 = (t&7)*32
  int r = t >> 3, e0 = (t & 7) * 32;
  const float* WvB = W + (long long)(512 + h * 32) * 256;
  unsigned* ebase = (unsigned*)(Eh + ((long long)(b * 256 + h * 32 + r)) * 256 + e0);
  #pragma unroll 4
  for (int eo = 0; eo < 32; eo += 2) {
    float a0 = 0.f, a1 = 0.f;
    for (int s = 0; s < 32; s++) {
      float ws_ = wsm[r][s];
      const float* wr = WvB + s * 256 + e0 + eo;
      a0 += ws_ * wr[0];
      a1 += ws_ * wr[1];
    }
    ebase[eo >> 1] = (unsigned)f2b(a0) | ((unsigned)f2b(a1) << 16);
  }
}

// K4: out_attn = E . T + bE  (replaces the v GEMM + k_pv: kv never exists).
// Round-5 counted-vmcnt dbuf GEMM: M=256(c_out) N=4096(n) K=256(e) per batch.
// A = Eh (bf16-hi), B = Th + Tl (2-term). 512 thr / 8 waves, 48KB LDS dbuf.
__global__ __launch_bounds__(512, 4) void k_out(
    const unsigned short* __restrict__ Eh, const unsigned short* __restrict__ Tn,
    const float* __restrict__ logits,  // bE overlay at [bh*1024 + r]
    float* __restrict__ out) {
  extern __shared__ unsigned short sm[];
  const int BUFS = 12288;  // u16 per buffer: Eh 8KB | Th 8KB | Tl 8KB
  int bx = blockIdx.x;
  int nt = bx & 31, mt = (bx >> 5) & 1, b = bx >> 6;
  int n0 = nt * 128, m0 = mt * 128;
  int t = threadIdx.x, lane = t & 63, w = t >> 6;
  int wm = w >> 2, wn = w & 3;
  int l15 = lane & 15, l4 = lane >> 4;
  const unsigned short* Thb = Tn + (long long)b * 2097152;
  const unsigned short* Tlb = Thb + 1048576;
  const unsigned short* Ehb = Eh + (long long)b * 65536;

  // 24 chunks (16 rows x 32 u16): 0-7 Eh(m0..), 8-15 Th(n0..), 16-23 Tl(n0..)
  const unsigned short* csrc[3];
  int dsto[3];
  int lrow = lane >> 2;
  int lslot = ((lane & 3) ^ ((lane >> 3) & 3)) * 8;
  #pragma unroll
  for (int i = 0; i < 3; i++) {
    int c = w + 8 * i;
    const unsigned short* plane = (c < 8) ? Ehb : ((c < 16) ? Thb : Tlb);
    int rowb = (c < 8) ? (m0 + c * 16) : ((c < 16) ? (n0 + (c - 8) * 16)
                                                   : (n0 + (c - 16) * 16));
    csrc[i] = plane + (long long)(rowb + lrow) * 256 + lslot;
    dsto[i] = c * 512;
  }
  int sw = (l4 ^ ((l15 >> 1) & 3)) << 3;

  f32x4 z = {0.f, 0.f, 0.f, 0.f};
  f32x4 acc[4][2];
  #pragma unroll
  for (int i = 0; i < 4; i++)
    #pragma unroll
    for (int j = 0; j < 2; j++) acc[i][j] = z;

  #pragma unroll
  for (int i = 0; i < 3; i++) gload16(csrc[i], sm + dsto[i]);

  int cur = 0;
  for (int step = 0; step < 8; ++step) {
    if (step < 7) {
      unsigned short* dp = sm + (cur ^ 1) * BUFS;
      int k0 = (step + 1) * 32;
      #pragma unroll
      for (int i = 0; i < 3; i++) gload16(csrc[i] + k0, dp + dsto[i]);
      asm volatile("s_waitcnt vmcnt(3)" ::: "memory");
    } else {
      asm volatile("s_waitcnt vmcnt(0)" ::: "memory");
    }
    __builtin_amdgcn_s_barrier();
    __builtin_amdgcn_sched_barrier(0);
    unsigned short* base = sm + cur * BUFS;
    bf16x8 ah[4], bh[2], bl[2];
    #pragma unroll
    for (int i = 0; i < 4; i++)
      ah[i] = *(const bf16x8*)(base + (wm * 64 + i * 16 + l15) * 32 + sw);
    #pragma unroll
    for (int j = 0; j < 2; j++) {
      int ro = (wn * 32 + j * 16 + l15) * 32 + sw;
      bh[j] = *(const bf16x8*)(base + 4096 + ro);
      bl[j] = *(const bf16x8*)(base + 8192 + ro);
    }
    #pragma unroll
    for (int i = 0; i < 4; i++)
      #pragma unroll
      for (int j = 0; j < 2; j++) {
        acc[i][j] = __builtin_amdgcn_mfma_f32_16x16x32_bf16(ah[i], bh[j], acc[i][j], 0, 0, 0);
        acc[i][j] = __builtin_amdgcn_mfma_f32_16x16x32_bf16(ah[i], bl[j], acc[i][j], 0, 0, 0);
      }
    __builtin_amdgcn_sched_barrier(0);
    __builtin_amdgcn_s_barrier();
    cur ^= 1;
  }

  #pragma unroll
  for (int i = 0; i < 4; i++) {
    #pragma unroll
    for (int r = 0; r < 4; r++) {
      int co = m0 + wm * 64 + i * 16 + l4 * 4 + r;
      float be = logits[(long long)(b * 8 + (co >> 5)) * 1024 + (co & 31)];
      #pragma unroll
      for (int j = 0; j < 2; j++) {
        int n = n0 + wn * 32 + j * 16 + l15;
        out[((long long)(b * 512 + 256 + co)) * 4096 + n] = acc[i][j][r] + be;
      }
    }
  }
}

extern "C" void kernel_launch(void* const* d_in, const int* in_sizes, int n_in,
                              void* d_out, int out_size, void* d_ws, size_t ws_size,
                              hipStream_t stream) {
  const float* x    = (const float*)d_in[0];
  const float* modm = (const float*)d_in[1];
  const float* modb = (const float*)d_in[2];
  const float* Wq   = (const float*)d_in[3];
  const float* qkvb = (const float*)d_in[4];
  const float* peqh = (const float*)d_in[5];
  const float* peqw = (const float*)d_in[6];
  const float* pekh = (const float*)d_in[7];
  const float* pekw = (const float*)d_in[8];
  const float* pab  = (const float*)d_in[9];
  const float* pqb  = (const float*)d_in[10];
  float* out = (float*)d_out;

  // ws layout (exactly 67 MiB = round-6/7-proven bound):
  //   [0, 64Mi)          Tn: per b {Th u16[4096][256], Tl u16[4096][256]} (4MiB/b)
  //   [64Mi, 64.5Mi)     Wh/Wl u16[512][256] (q,k rows; 256KiB each)
  //   [64.5Mi, 65Mi)     logits f32[16][8][32][32]; after k_corr, [bh][0:32] = bE
  //   [65Mi, 67Mi)       Eh u16[16][256][256] (weights . Wv, bf16-hi)
  unsigned short* Tn = (unsigned short*)d_ws;
  unsigned short* Wh = (unsigned short*)((char*)d_ws + 67108864);
  unsigned short* Wl = Wh + 131072;
  float* logits = (float*)((char*)d_ws + 67633152);
  unsigned short* Eh = (unsigned short*)((char*)d_ws + 68157440);

  hipMemsetAsync(logits, 0, 524288, stream);
  k_prep<<<4160, 256, 0, stream>>>(x, pab, pqb, Wq, Wh, Wl, Tn, out);
  k_qkl<<<4096, 256, 0, stream>>>(Wh, Wl, qkvb, peqh, peqw, pekh, pekw,
                                  modm, modb, Tn, logits);
  k_corr<<<128, 256, 0, stream>>>(logits, Wq, qkvb, Eh);
  k_out<<<1024, 512, 49152, stream>>>(Eh, Tn, logits, out);
}

// Round 10
// 371.040 us; speedup vs baseline: 1.0163x; 1.0163x over previous
//
#include <hip/hip_runtime.h>

typedef short bf16x8 __attribute__((ext_vector_type(8)));
typedef float f32x4 __attribute__((ext_vector_type(4)));

__device__ __forceinline__ float b2f(unsigned short u) {
  union { unsigned int i; float f; } v; v.i = ((unsigned int)u) << 16; return v.f;
}
__device__ __forceinline__ unsigned short f2b(float f) {
  unsigned int u = __float_as_uint(f);
  u += 0x7fffu + ((u >> 16) & 1u);
  return (unsigned short)(u >> 16);
}
__device__ __forceinline__ float silu_f(float s) { return s / (1.0f + __expf(-s)); }

// split fp32 -> (hi, lo) bf16
__device__ __forceinline__ void split2(float f, unsigned short& h, unsigned short& l) {
  h = f2b(f);
  l = f2b(f - b2f(h));
}

// async 16B/lane global->LDS. LDS dest = wave-uniform base + lane*16 (linear).
__device__ __forceinline__ void gload16(const unsigned short* g, unsigned short* l) {
  __builtin_amdgcn_global_load_lds(
      (const __attribute__((address_space(1))) unsigned int*)g,
      (__attribute__((address_space(3))) unsigned int*)l, 16, 0, 0);
}

// unpack 8 packed (hi | lo<<16) u32 -> hi/lo bf16x8 via v_perm (2 ops per pair)
__device__ __forceinline__ void unpack8(const unsigned* p, bf16x8& hi, bf16x8& lo) {
  uint4 a = *(const uint4*)p;
  uint4 b = *(const uint4*)(p + 4);
  unsigned u[8] = {a.x, a.y, a.z, a.w, b.x, b.y, b.z, b.w};
  unsigned hw[4], lw[4];
  #pragma unroll
  for (int j = 0; j < 4; j++) {
    hw[j] = __builtin_amdgcn_perm(u[2 * j + 1], u[2 * j], 0x05040100u);
    lw[j] = __builtin_amdgcn_perm(u[2 * j + 1], u[2 * j], 0x07060302u);
  }
  hi = *(bf16x8*)hw;
  lo = *(bf16x8*)lw;
}

// K0: split W fp32 -> Wh/Wl bf16 planes [768][256], once.
__global__ __launch_bounds__(256) void k_wsplit(
    const float* __restrict__ W, unsigned short* __restrict__ Wh,
    unsigned short* __restrict__ Wl) {
  int e = (blockIdx.x * 256 + threadIdx.x) * 8;  // 96 blocks * 256 * 8 = 768*256
  float4 a = *(const float4*)(W + e);
  float4 b = *(const float4*)(W + e + 4);
  float v[8] = {a.x, a.y, a.z, a.w, b.x, b.y, b.z, b.w};
  unsigned short h[8], l[8];
  #pragma unroll
  for (int j = 0; j < 8; j++) split2(v[j], h[j], l[j]);
  uint4 ph, pl;
  ph.x = h[0] | ((unsigned)h[1] << 16); ph.y = h[2] | ((unsigned)h[3] << 16);
  ph.z = h[4] | ((unsigned)h[5] << 16); ph.w = h[6] | ((unsigned)h[7] << 16);
  pl.x = l[0] | ((unsigned)l[1] << 16); pl.y = l[2] | ((unsigned)l[3] << 16);
  pl.z = l[4] | ((unsigned)l[5] << 16); pl.w = l[6] | ((unsigned)l[7] << 16);
  *(uint4*)(Wh + e) = ph;
  *(uint4*)(Wl + e) = pl;
}

// K1: fused prep+act:
//   x_preact = silu(x + pab) fp32 -> out[:,0:256]
//   T = x_preact + pqb, TRANSPOSED split planes -> out[:,256:512]
//     per batch: Th u16[4096][256] then Tl u16[4096][256]
__global__ __launch_bounds__(256) void k_prep(
    const float* __restrict__ x, const float* __restrict__ pab,
    const float* __restrict__ pqb, float* __restrict__ out) {
  __shared__ unsigned short th[64 * 64], tl[64 * 64];  // [n][c], sub-chunk swizzled
  int blk = blockIdx.x;
  int nb = blk & 63;
  int cb = (blk >> 6) & 3;
  int b = blk >> 8;
  int n0 = nb * 64, c0 = cb * 64;
  int t = threadIdx.x;
  int nn = (t & 15) * 4;
  #pragma unroll
  for (int p = 0; p < 2; p++) {
    int c = 2 * (p * 16 + (t >> 4));  // even
    float pa0 = pab[c0 + c], pq0 = pqb[c0 + c];
    float pa1 = pab[c0 + c + 1], pq1 = pqb[c0 + c + 1];
    float4 x0 = *(const float4*)(x + ((long long)(b * 256 + c0 + c)) * 4096 + n0 + nn);
    float4 x1 = *(const float4*)(x + ((long long)(b * 256 + c0 + c + 1)) * 4096 + n0 + nn);
    float s0[4] = {silu_f(x0.x + pa0), silu_f(x0.y + pa0),
                   silu_f(x0.z + pa0), silu_f(x0.w + pa0)};
    float s1[4] = {silu_f(x1.x + pa1), silu_f(x1.y + pa1),
                   silu_f(x1.z + pa1), silu_f(x1.w + pa1)};
    float4 sv0 = {s0[0], s0[1], s0[2], s0[3]};
    float4 sv1 = {s1[0], s1[1], s1[2], s1[3]};
    *(float4*)(out + ((long long)(b * 512 + c0 + c)) * 4096 + n0 + nn) = sv0;
    *(float4*)(out + ((long long)(b * 512 + c0 + c + 1)) * 4096 + n0 + nn) = sv1;
    float t0[4] = {s0[0] + pq0, s0[1] + pq0, s0[2] + pq0, s0[3] + pq0};
    float t1[4] = {s1[0] + pq1, s1[1] + pq1, s1[2] + pq1, s1[3] + pq1};
    #pragma unroll
    for (int j = 0; j < 4; j++) {
      int nr = nn + j;
      unsigned short h0, l0, h1, l1;
      split2(t0[j], h0, l0);
      split2(t1[j], h1, l1);
      int pcol = ((((c >> 3) ^ (nr & 7)) << 3) | (c & 7));
      *(unsigned int*)(th + nr * 64 + pcol) = (unsigned)h0 | ((unsigned)h1 << 16);
      *(unsigned int*)(tl + nr * 64 + pcol) = (unsigned)l0 | ((unsigned)l1 << 16);
    }
  }
  __syncthreads();
  unsigned short* Th = (unsigned short*)(out + ((long long)(b * 512 + 256)) * 4096);
  unsigned short* Tl = Th + 4096 * 256;
  #pragma unroll
  for (int q = 0; q < 2; q++) {
    int s = q * 256 + t;
    int n = s >> 3, sc = s & 7;
    int psc = sc ^ (n & 7);
    uint4 vh = *(const uint4*)(th + n * 64 + psc * 8);
    uint4 vl = *(const uint4*)(tl + n * 64 + psc * 8);
    *(uint4*)(Th + (long long)(n0 + n) * 256 + c0 + sc * 8) = vh;
    *(uint4*)(Tl + (long long)(n0 + n) * 256 + c0 + sc * 8) = vl;
  }
}

// K2: fused q/k/v GEMM + logits. One block = (b, head, ntile of 128 n).
// Main loop stages 26 x 1KB chunks (Ah q/k, Al q/k, Av v-hi, Bh, Bl) and runs
//   qk: 3-term split-bf16; v: 1-term hi-only (both bit-identical to R7)
// Epilogue: v -> kv fp32; q/k + bias + PE (+FiLM) packed -> swizzled qk LDS tile.
// Logits: q.k^T over this n-tile, cross-wave LDS reduce, atomicAdd into logits.
// LDS 32KB overlay (5 blocks/CU); __launch_bounds__(256,5): VGPR cap 102 >> 64
// used (no spill), occupancy hint 20 waves/CU (was (256,3) -> 40% measured).
__global__ __launch_bounds__(256, 5) void k_qkl(
    const unsigned short* __restrict__ Wh, const unsigned short* __restrict__ Wl,
    const float* __restrict__ qkvb,
    const float* __restrict__ peqh, const float* __restrict__ peqw,
    const float* __restrict__ pekh, const float* __restrict__ pekw,
    const float* __restrict__ modm, const float* __restrict__ modb,
    const float* __restrict__ outT, float* __restrict__ kv,
    float* __restrict__ logits) {
  __shared__ __align__(16) unsigned char smem[32768];
  unsigned short* stg = (unsigned short*)smem;  // main loop: 26KB
  unsigned* qk = (unsigned*)smem;               // logits operand tile: 32KB
  float* red = (float*)smem;                    // cross-wave reduce: 16KB

  int bx = blockIdx.x;
  int ntile = bx & 31, h = (bx >> 5) & 7, b = bx >> 8;
  int n0 = ntile * 128;
  int t = threadIdx.x, lane = t & 63, w = t >> 6;
  int l15 = lane & 15, l4 = lane >> 4;

  const unsigned short* Th =
      (const unsigned short*)(outT + ((long long)(b * 512 + 256)) * 4096);
  const unsigned short* Tl = Th + 4096 * 256;

  // chunk c (16 rows x 32 u16 = 1KB): 0-3 Ah(q,q,k,k), 4-7 Al(q,q,k,k),
  // 8-9 Av(v,v), 10-17 Bh, 18-25 Bl. u16 LDS offsets: Ah 0, Al 2048, Av 4096,
  // Bh 5120, Bl 9216. Wave w stages c = w, w+4, ... (waves 0,1: 7; 2,3: 6).
  const unsigned short* csrc[7];
  unsigned short* cdst[7];
  int nc = (w < 2) ? 7 : 6;
  int lrow = lane >> 2;
  int lslot = ((lane & 3) ^ ((lane >> 3) & 3)) * 8;  // source-side swizzle
  #pragma unroll
  for (int i = 0; i < 7; i++) {
    int c = w + 4 * i;
    if (c > 25) c = 25;  // dummy (not issued)
    const unsigned short* plane;
    int rowb, ldsoff;
    if (c < 4) {
      plane = Wh; rowb = ((c & 2) ? 256 : 0) + h * 32 + (c & 1) * 16;
      ldsoff = c * 512;
    } else if (c < 8) {
      int s2 = c - 4;
      plane = Wl; rowb = ((s2 & 2) ? 256 : 0) + h * 32 + (s2 & 1) * 16;
      ldsoff = c * 512;
    } else if (c < 10) {
      plane = Wh; rowb = 512 + h * 32 + (c - 8) * 16;
      ldsoff = 4096 + (c - 8) * 512;
    } else if (c < 18) {
      plane = Th; rowb = n0 + (c - 10) * 16;
      ldsoff = 5120 + (c - 10) * 512;
    } else {
      plane = Tl; rowb = n0 + (c - 18) * 16;
      ldsoff = 9216 + (c - 18) * 512;
    }
    csrc[i] = plane + (long long)(rowb + lrow) * 256 + lslot;
    cdst[i] = stg + ldsoff;
  }

  int sw = (l4 ^ ((l15 >> 1) & 3)) << 3;  // read-side swizzle
  f32x4 z = {0.f, 0.f, 0.f, 0.f};
  f32x4 acc[4][2];   // q/k rows 0..63
  f32x4 accv[2][2];  // v rows 0..31
  #pragma unroll
  for (int i = 0; i < 4; i++)
    #pragma unroll
    for (int j = 0; j < 2; j++) acc[i][j] = z;
  #pragma unroll
  for (int i = 0; i < 2; i++)
    #pragma unroll
    for (int j = 0; j < 2; j++) accv[i][j] = z;

  for (int step = 0; step < 8; ++step) {
    int k0 = step * 32;
    #pragma unroll
    for (int i = 0; i < 7; i++)
      if (i < nc) gload16(csrc[i] + k0, cdst[i]);
    __syncthreads();
    // v phase first (av dies early -> lower peak VGPR)
    bf16x8 bh[2], av[2];
    #pragma unroll
    for (int j = 0; j < 2; j++)
      bh[j] = *(const bf16x8*)(stg + 5120 + (w * 32 + j * 16 + l15) * 32 + sw);
    #pragma unroll
    for (int i = 0; i < 2; i++)
      av[i] = *(const bf16x8*)(stg + 4096 + (i * 16 + l15) * 32 + sw);
    #pragma unroll
    for (int i = 0; i < 2; i++)
      #pragma unroll
      for (int j = 0; j < 2; j++)
        accv[i][j] = __builtin_amdgcn_mfma_f32_16x16x32_bf16(av[i], bh[j], accv[i][j], 0, 0, 0);
    __builtin_amdgcn_sched_barrier(0);
    // qk phase (3-term)
    bf16x8 ah[4], al[4], bl[2];
    #pragma unroll
    for (int i = 0; i < 4; i++) {
      int ro = (i * 16 + l15) * 32 + sw;
      ah[i] = *(const bf16x8*)(stg + ro);
      al[i] = *(const bf16x8*)(stg + 2048 + ro);
    }
    #pragma unroll
    for (int j = 0; j < 2; j++)
      bl[j] = *(const bf16x8*)(stg + 9216 + (w * 32 + j * 16 + l15) * 32 + sw);
    #pragma unroll
    for (int i = 0; i < 4; i++)
      #pragma unroll
      for (int j = 0; j < 2; j++) {
        acc[i][j] = __builtin_amdgcn_mfma_f32_16x16x32_bf16(ah[i], bh[j], acc[i][j], 0, 0, 0);
        acc[i][j] = __builtin_amdgcn_mfma_f32_16x16x32_bf16(ah[i], bl[j], acc[i][j], 0, 0, 0);
        acc[i][j] = __builtin_amdgcn_mfma_f32_16x16x32_bf16(al[i], bh[j], acc[i][j], 0, 0, 0);
      }
    __syncthreads();
  }

  // v epilogue: bias only -> kv fp32 (frees accv)
  int b256 = b * 256;
  #pragma unroll
  for (int i = 0; i < 2; i++) {
    #pragma unroll
    for (int r = 0; r < 4; r++) {
      int row = i * 16 + l4 * 4 + r;  // 0..31
      int cch = h * 32 + row;
      float bias = qkvb[512 + cch];
      #pragma unroll
      for (int j = 0; j < 2; j++) {
        int n = n0 + w * 32 + j * 16 + l15;
        kv[((long long)(b256 + cch)) * 4096 + n] = accv[i][j][r] + bias;
      }
    }
  }

  // q/k epilogue: bias + PE (+FiLM for q), pack, store to swizzled qk tile
  #pragma unroll
  for (int i = 0; i < 4; i++) {
    #pragma unroll
    for (int r = 0; r < 4; r++) {
      int row = i * 16 + l4 * 4 + r;  // 0..63; i<2 -> q, i>=2 -> k
      int cch = h * 32 + (row & 31);
      float bias = qkvb[(row & 32) ? (256 + cch) : cch];
      float mm = 0.f, mb = 0.f;
      if (row < 32) { mm = modm[b256 + cch]; mb = modb[b256 + cch]; }
      #pragma unroll
      for (int j = 0; j < 2; j++) {
        int nl = w * 32 + j * 16 + l15;
        int n = n0 + nl;
        int hh = n >> 6, ww = n & 63;
        float v = acc[i][j][r] + bias;
        if (row < 32) {
          v += peqh[cch * 64 + hh] + peqw[cch * 64 + ww];
          v = v * mm + mb;
        } else {
          v += pekh[cch * 64 + hh] + pekw[cch * 64 + ww];
        }
        unsigned short hi_, lo_;
        split2(v, hi_, lo_);
        int pch = (nl >> 3) ^ (row & 15);  // chunk swizzle (8 u32 = 32B chunks)
        qk[row * 128 + pch * 8 + (nl & 7)] = (unsigned)hi_ | ((unsigned)lo_ << 16);
      }
    }
  }
  __syncthreads();

  // logits partial: q(32 x 128n) . k(32 x 128n)^T; wave w covers n-slice w*32..
  f32x4 acc2[2][2] = {z, z, z, z};
  int chn = w * 4 + l4;
  bf16x8 qh[2], ql[2], kh[2], kl[2];
  #pragma unroll
  for (int i2 = 0; i2 < 2; i2++) {
    int row = i2 * 16 + l15;
    unpack8(qk + row * 128 + ((chn ^ l15) << 3), qh[i2], ql[i2]);
    unpack8(qk + (row + 32) * 128 + ((chn ^ l15) << 3), kh[i2], kl[i2]);
  }
  acc2[0][0] = __builtin_amdgcn_mfma_f32_16x16x32_bf16(qh[0], kh[0], acc2[0][0], 0, 0, 0);
  acc2[0][0] = __builtin_amdgcn_mfma_f32_16x16x32_bf16(qh[0], kl[0], acc2[0][0], 0, 0, 0);
  acc2[0][0] = __builtin_amdgcn_mfma_f32_16x16x32_bf16(ql[0], kh[0], acc2[0][0], 0, 0, 0);
  acc2[0][1] = __builtin_amdgcn_mfma_f32_16x16x32_bf16(qh[0], kh[1], acc2[0][1], 0, 0, 0);
  acc2[0][1] = __builtin_amdgcn_mfma_f32_16x16x32_bf16(qh[0], kl[1], acc2[0][1], 0, 0, 0);
  acc2[0][1] = __builtin_amdgcn_mfma_f32_16x16x32_bf16(ql[0], kh[1], acc2[0][1], 0, 0, 0);
  acc2[1][0] = __builtin_amdgcn_mfma_f32_16x16x32_bf16(qh[1], kh[0], acc2[1][0], 0, 0, 0);
  acc2[1][0] = __builtin_amdgcn_mfma_f32_16x16x32_bf16(qh[1], kl[0], acc2[1][0], 0, 0, 0);
  acc2[1][0] = __builtin_amdgcn_mfma_f32_16x16x32_bf16(ql[1], kh[0], acc2[1][0], 0, 0, 0);
  acc2[1][1] = __builtin_amdgcn_mfma_f32_16x16x32_bf16(qh[1], kh[1], acc2[1][1], 0, 0, 0);
  acc2[1][1] = __builtin_amdgcn_mfma_f32_16x16x32_bf16(qh[1], kl[1], acc2[1][1], 0, 0, 0);
  acc2[1][1] = __builtin_amdgcn_mfma_f32_16x16x32_bf16(ql[1], kh[1], acc2[1][1], 0, 0, 0);

  // red aliases qk: wait for ALL waves' qk reads before overwriting
  __syncthreads();
  #pragma unroll
  for (int i2 = 0; i2 < 2; i2++)
    #pragma unroll
    for (int j2 = 0; j2 < 2; j2++)
      #pragma unroll
      for (int r = 0; r < 4; r++)
        red[w * 1024 + (i2 * 16 + l4 * 4 + r) * 32 + j2 * 16 + l15] = acc2[i2][j2][r];
  __syncthreads();
  const float scale = 0.1767766952966369f;  // 1/sqrt(32)
  int bhid = b * 8 + h;
  #pragma unroll
  for (int i = 0; i < 4; i++) {
    int idx = i * 256 + t;
    float s = (red[idx] + red[1024 + idx] + red[2048 + idx] + red[3072 + idx]) * scale;
    atomicAdd(logits + (long long)bhid * 1024 + idx, s);
  }
}

// K3: softmax (logits already summed by atomics, already scaled) + weights @ v
__global__ __launch_bounds__(256) void k_pv(
    const float* __restrict__ kv,    // v
    const float* __restrict__ logits,
    float* __restrict__ out) {
  int bx = blockIdx.x;
  int ntile = bx & 15, bh = bx >> 4;
  int b = bh >> 3, h = bh & 7;
  int t = threadIdx.x;
  __shared__ float raw[32][33];   // [c][d], padded: serial reads conflict-free
  __shared__ float wsm[32][33];
  #pragma unroll
  for (int i = 0; i < 4; i++) {
    int idx = i * 256 + t;
    raw[idx >> 5][idx & 31] = logits[(long long)bh * 1024 + idx];
  }
  __syncthreads();
  if (t < 32) {
    float mx = -1e30f;
    for (int d = 0; d < 32; d++) mx = fmaxf(mx, raw[t][d]);
    float e[32]; float s = 0.f;
    for (int d = 0; d < 32; d++) { e[d] = __expf(raw[t][d] - mx); s += e[d]; }
    float inv = 1.0f / s;
    for (int d = 0; d < 32; d++) wsm[t][d] = e[d] * inv;
  }
  __syncthreads();
  int rg = t >> 6;          // wave-uniform -> wsm broadcast
  int nl = (t & 63) * 4;
  int n0 = ntile * 256 + nl;
  const float* vb = kv + ((long long)(b * 256 + h * 32)) * 4096 + n0;
  float acc[8][4];
  #pragma unroll
  for (int r = 0; r < 8; r++)
    #pragma unroll
    for (int i = 0; i < 4; i++) acc[r][i] = 0.f;
  for (int d = 0; d < 32; d++) {
    float4 vv = *(const float4*)(vb + (long long)d * 4096);
    #pragma unroll
    for (int r = 0; r < 8; r++) {
      float wv = wsm[rg * 8 + r][d];
      acc[r][0] += wv * vv.x; acc[r][1] += wv * vv.y;
      acc[r][2] += wv * vv.z; acc[r][3] += wv * vv.w;
    }
  }
  #pragma unroll
  for (int r = 0; r < 8; r++) {
    long long oidx = ((long long)(b * 512 + 256 + h * 32 + rg * 8 + r)) * 4096 + n0;
    float4 ov = {acc[r][0], acc[r][1], acc[r][2], acc[r][3]};
    *(float4*)(out + oidx) = ov;
  }
}

extern "C" void kernel_launch(void* const* d_in, const int* in_sizes, int n_in,
                              void* d_out, int out_size, void* d_ws, size_t ws_size,
                              hipStream_t stream) {
  const float* x    = (const float*)d_in[0];
  const float* modm = (const float*)d_in[1];
  const float* modb = (const float*)d_in[2];
  const float* Wq   = (const float*)d_in[3];
  const float* qkvb = (const float*)d_in[4];
  const float* peqh = (const float*)d_in[5];
  const float* peqw = (const float*)d_in[6];
  const float* pekh = (const float*)d_in[7];
  const float* pekw = (const float*)d_in[8];
  const float* pab  = (const float*)d_in[9];
  const float* pqb  = (const float*)d_in[10];
  float* out = (float*)d_out;

  // ws layout (67 MB total, <= 69.2 MB proven):
  //   [0, 0.75MB)    Wh/Wl u16[768][256] split-bf16 planes
  //   [1MB, 1.5MB)   logits f32[16][8][32][32] (atomic-accumulated, pre-scaled)
  //   [3MB, 67MB)    v fp32 [16][256][4096]
  unsigned short* Wh = (unsigned short*)d_ws;
  unsigned short* Wl = Wh + 768 * 256;
  float* logits = (float*)((char*)d_ws + (1 << 20));
  float* kv = (float*)((char*)d_ws + 3 * (1 << 20));

  hipMemsetAsync(logits, 0, 524288, stream);
  k_wsplit<<<96, 256, 0, stream>>>(Wq, Wh, Wl);
  k_prep<<<4096, 256, 0, stream>>>(x, pab, pqb, out);
  k_qkl<<<4096, 256, 0, stream>>>(Wh, Wl, qkvb, peqh, peqw, pekh, pekw,
                                  modm, modb, out, kv, logits);
  k_pv<<<2048, 256, 0, stream>>>(kv, logits, out);
}

// Round 11
// 316.566 us; speedup vs baseline: 1.1912x; 1.1721x over previous
//
#include <hip/hip_runtime.h>

typedef short bf16x8 __attribute__((ext_vector_type(8)));
typedef float f32x4 __attribute__((ext_vector_type(4)));

__device__ __forceinline__ float b2f(unsigned short u) {
  union { unsigned int i; float f; } v; v.i = ((unsigned int)u) << 16; return v.f;
}
__device__ __forceinline__ unsigned short f2b(float f) {
  unsigned int u = __float_as_uint(f);
  u += 0x7fffu + ((u >> 16) & 1u);
  return (unsigned short)(u >> 16);
}
__device__ __forceinline__ float silu_f(float s) { return s / (1.0f + __expf(-s)); }

// split fp32 -> (hi, lo) bf16
__device__ __forceinline__ void split2(float f, unsigned short& h, unsigned short& l) {
  h = f2b(f);
  l = f2b(f - b2f(h));
}

// async 16B/lane global->LDS. LDS dest = wave-uniform base + lane*16 (linear).
__device__ __forceinline__ void gload16(const unsigned short* g, unsigned short* l) {
  __builtin_amdgcn_global_load_lds(
      (const __attribute__((address_space(1))) unsigned int*)g,
      (__attribute__((address_space(3))) unsigned int*)l, 16, 0, 0);
}

// unpack 8 packed (hi | lo<<16) u32 -> hi/lo bf16x8 via v_perm (2 ops per pair)
__device__ __forceinline__ void unpack8(const unsigned* p, bf16x8& hi, bf16x8& lo) {
  uint4 a = *(const uint4*)p;
  uint4 b = *(const uint4*)(p + 4);
  unsigned u[8] = {a.x, a.y, a.z, a.w, b.x, b.y, b.z, b.w};
  unsigned hw[4], lw[4];
  #pragma unroll
  for (int j = 0; j < 4; j++) {
    hw[j] = __builtin_amdgcn_perm(u[2 * j + 1], u[2 * j], 0x05040100u);
    lw[j] = __builtin_amdgcn_perm(u[2 * j + 1], u[2 * j], 0x07060302u);
  }
  hi = *(bf16x8*)hw;
  lo = *(bf16x8*)lw;
}

// K1 (fused): blocks 0..95: W fp32 -> Wh/Wl bf16 planes [768][256] (was k_wsplit).
// blocks 96..: prep+act:
//   x_preact = silu(x + pab) fp32 -> out[:,0:256]
//   T = x_preact + pqb, TRANSPOSED split planes -> out[:,256:512]
//     per batch: Th u16[4096][256] then Tl u16[4096][256]
__global__ __launch_bounds__(256) void k_prep(
    const float* __restrict__ x, const float* __restrict__ pab,
    const float* __restrict__ pqb, const float* __restrict__ W,
    unsigned short* __restrict__ Wh, unsigned short* __restrict__ Wl,
    float* __restrict__ out) {
  __shared__ unsigned short th[64 * 64], tl[64 * 64];  // [n][c], sub-chunk swizzled
  int blk = blockIdx.x;
  if (blk < 96) {  // ---- W split: 96 * 256 * 8 = 768*256 elements ----
    int e = (blk * 256 + threadIdx.x) * 8;
    float4 a = *(const float4*)(W + e);
    float4 bq = *(const float4*)(W + e + 4);
    float v[8] = {a.x, a.y, a.z, a.w, bq.x, bq.y, bq.z, bq.w};
    unsigned short h8[8], l8[8];
    #pragma unroll
    for (int j = 0; j < 8; j++) split2(v[j], h8[j], l8[j]);
    uint4 ph, pl;
    ph.x = h8[0] | ((unsigned)h8[1] << 16); ph.y = h8[2] | ((unsigned)h8[3] << 16);
    ph.z = h8[4] | ((unsigned)h8[5] << 16); ph.w = h8[6] | ((unsigned)h8[7] << 16);
    pl.x = l8[0] | ((unsigned)l8[1] << 16); pl.y = l8[2] | ((unsigned)l8[3] << 16);
    pl.z = l8[4] | ((unsigned)l8[5] << 16); pl.w = l8[6] | ((unsigned)l8[7] << 16);
    *(uint4*)(Wh + e) = ph;
    *(uint4*)(Wl + e) = pl;
    return;
  }
  blk -= 96;  // ---- prep ----
  int nb = blk & 63;
  int cb = (blk >> 6) & 3;
  int b = blk >> 8;
  int n0 = nb * 64, c0 = cb * 64;
  int t = threadIdx.x;
  int nn = (t & 15) * 4;
  #pragma unroll
  for (int p = 0; p < 2; p++) {
    int c = 2 * (p * 16 + (t >> 4));  // even
    float pa0 = pab[c0 + c], pq0 = pqb[c0 + c];
    float pa1 = pab[c0 + c + 1], pq1 = pqb[c0 + c + 1];
    float4 x0 = *(const float4*)(x + ((long long)(b * 256 + c0 + c)) * 4096 + n0 + nn);
    float4 x1 = *(const float4*)(x + ((long long)(b * 256 + c0 + c + 1)) * 4096 + n0 + nn);
    float s0[4] = {silu_f(x0.x + pa0), silu_f(x0.y + pa0),
                   silu_f(x0.z + pa0), silu_f(x0.w + pa0)};
    float s1[4] = {silu_f(x1.x + pa1), silu_f(x1.y + pa1),
                   silu_f(x1.z + pa1), silu_f(x1.w + pa1)};
    float4 sv0 = {s0[0], s0[1], s0[2], s0[3]};
    float4 sv1 = {s1[0], s1[1], s1[2], s1[3]};
    *(float4*)(out + ((long long)(b * 512 + c0 + c)) * 4096 + n0 + nn) = sv0;
    *(float4*)(out + ((long long)(b * 512 + c0 + c + 1)) * 4096 + n0 + nn) = sv1;
    float t0[4] = {s0[0] + pq0, s0[1] + pq0, s0[2] + pq0, s0[3] + pq0};
    float t1[4] = {s1[0] + pq1, s1[1] + pq1, s1[2] + pq1, s1[3] + pq1};
    #pragma unroll
    for (int j = 0; j < 4; j++) {
      int nr = nn + j;
      unsigned short h0, l0, h1, l1;
      split2(t0[j], h0, l0);
      split2(t1[j], h1, l1);
      int pcol = ((((c >> 3) ^ (nr & 7)) << 3) | (c & 7));
      *(unsigned int*)(th + nr * 64 + pcol) = (unsigned)h0 | ((unsigned)h1 << 16);
      *(unsigned int*)(tl + nr * 64 + pcol) = (unsigned)l0 | ((unsigned)l1 << 16);
    }
  }
  __syncthreads();
  unsigned short* Th = (unsigned short*)(out + ((long long)(b * 512 + 256)) * 4096);
  unsigned short* Tl = Th + 4096 * 256;
  #pragma unroll
  for (int q = 0; q < 2; q++) {
    int s = q * 256 + t;
    int n = s >> 3, sc = s & 7;
    int psc = sc ^ (n & 7);
    uint4 vh = *(const uint4*)(th + n * 64 + psc * 8);
    uint4 vl = *(const uint4*)(tl + n * 64 + psc * 8);
    *(uint4*)(Th + (long long)(n0 + n) * 256 + c0 + sc * 8) = vh;
    *(uint4*)(Tl + (long long)(n0 + n) * 256 + c0 + sc * 8) = vl;
  }
}

// K2: fused q/k/v GEMM + logits (R7 configuration — measured optimum).
// One block = (b, head, ntile of 128 n). Main loop stages 26 x 1KB chunks
// (Ah q/k, Al q/k, Av v-hi, Bh, Bl):
//   qk: 3-term split-bf16; v: 1-term hi-only
// Epilogue: v -> kv fp32; q/k + bias + PE (+FiLM) packed -> swizzled qk LDS tile.
// Logits: q.k^T over this n-tile, cross-wave LDS reduce, atomicAdd into logits.
// LDS 32KB overlay: stg(26KB) | qk(32KB) | red(16KB), phases barrier-separated.
// __launch_bounds__(256,3): measured no-spill point (R4/R10: tighter bounds spill).
__global__ __launch_bounds__(256, 3) void k_qkl(
    const unsigned short* __restrict__ Wh, const unsigned short* __restrict__ Wl,
    const float* __restrict__ qkvb,
    const float* __restrict__ peqh, const float* __restrict__ peqw,
    const float* __restrict__ pekh, const float* __restrict__ pekw,
    const float* __restrict__ modm, const float* __restrict__ modb,
    const float* __restrict__ outT, float* __restrict__ kv,
    float* __restrict__ logits) {
  __shared__ __align__(16) unsigned char smem[32768];
  unsigned short* stg = (unsigned short*)smem;  // main loop: 26KB
  unsigned* qk = (unsigned*)smem;               // logits operand tile: 32KB
  float* red = (float*)smem;                    // cross-wave reduce: 16KB

  int bx = blockIdx.x;
  int ntile = bx & 31, h = (bx >> 5) & 7, b = bx >> 8;
  int n0 = ntile * 128;
  int t = threadIdx.x, lane = t & 63, w = t >> 6;
  int l15 = lane & 15, l4 = lane >> 4;

  const unsigned short* Th =
      (const unsigned short*)(outT + ((long long)(b * 512 + 256)) * 4096);
  const unsigned short* Tl = Th + 4096 * 256;

  // chunk c (16 rows x 32 u16 = 1KB): 0-3 Ah(q,q,k,k), 4-7 Al(q,q,k,k),
  // 8-9 Av(v,v), 10-17 Bh, 18-25 Bl. u16 LDS offsets: Ah 0, Al 2048, Av 4096,
  // Bh 5120, Bl 9216. Wave w stages c = w, w+4, ... (waves 0,1: 7; 2,3: 6).
  const unsigned short* csrc[7];
  unsigned short* cdst[7];
  int nc = (w < 2) ? 7 : 6;
  int lrow = lane >> 2;
  int lslot = ((lane & 3) ^ ((lane >> 3) & 3)) * 8;  // source-side swizzle
  #pragma unroll
  for (int i = 0; i < 7; i++) {
    int c = w + 4 * i;
    if (c > 25) c = 25;  // dummy (not issued)
    const unsigned short* plane;
    int rowb, ldsoff;
    if (c < 4) {
      plane = Wh; rowb = ((c & 2) ? 256 : 0) + h * 32 + (c & 1) * 16;
      ldsoff = c * 512;
    } else if (c < 8) {
      int s2 = c - 4;
      plane = Wl; rowb = ((s2 & 2) ? 256 : 0) + h * 32 + (s2 & 1) * 16;
      ldsoff = c * 512;
    } else if (c < 10) {
      plane = Wh; rowb = 512 + h * 32 + (c - 8) * 16;
      ldsoff = 4096 + (c - 8) * 512;
    } else if (c < 18) {
      plane = Th; rowb = n0 + (c - 10) * 16;
      ldsoff = 5120 + (c - 10) * 512;
    } else {
      plane = Tl; rowb = n0 + (c - 18) * 16;
      ldsoff = 9216 + (c - 18) * 512;
    }
    csrc[i] = plane + (long long)(rowb + lrow) * 256 + lslot;
    cdst[i] = stg + ldsoff;
  }

  int sw = (l4 ^ ((l15 >> 1) & 3)) << 3;  // read-side swizzle
  f32x4 z = {0.f, 0.f, 0.f, 0.f};
  f32x4 acc[4][2];   // q/k rows 0..63
  f32x4 accv[2][2];  // v rows 0..31
  #pragma unroll
  for (int i = 0; i < 4; i++)
    #pragma unroll
    for (int j = 0; j < 2; j++) acc[i][j] = z;
  #pragma unroll
  for (int i = 0; i < 2; i++)
    #pragma unroll
    for (int j = 0; j < 2; j++) accv[i][j] = z;

  for (int step = 0; step < 8; ++step) {
    int k0 = step * 32;
    #pragma unroll
    for (int i = 0; i < 7; i++)
      if (i < nc) gload16(csrc[i] + k0, cdst[i]);
    __syncthreads();
    // v phase first (av dies early -> lower peak VGPR)
    bf16x8 bh[2], av[2];
    #pragma unroll
    for (int j = 0; j < 2; j++)
      bh[j] = *(const bf16x8*)(stg + 5120 + (w * 32 + j * 16 + l15) * 32 + sw);
    #pragma unroll
    for (int i = 0; i < 2; i++)
      av[i] = *(const bf16x8*)(stg + 4096 + (i * 16 + l15) * 32 + sw);
    #pragma unroll
    for (int i = 0; i < 2; i++)
      #pragma unroll
      for (int j = 0; j < 2; j++)
        accv[i][j] = __builtin_amdgcn_mfma_f32_16x16x32_bf16(av[i], bh[j], accv[i][j], 0, 0, 0);
    __builtin_amdgcn_sched_barrier(0);
    // qk phase (3-term)
    bf16x8 ah[4], al[4], bl[2];
    #pragma unroll
    for (int i = 0; i < 4; i++) {
      int ro = (i * 16 + l15) * 32 + sw;
      ah[i] = *(const bf16x8*)(stg + ro);
      al[i] = *(const bf16x8*)(stg + 2048 + ro);
    }
    #pragma unroll
    for (int j = 0; j < 2; j++)
      bl[j] = *(const bf16x8*)(stg + 9216 + (w * 32 + j * 16 + l15) * 32 + sw);
    #pragma unroll
    for (int i = 0; i < 4; i++)
      #pragma unroll
      for (int j = 0; j < 2; j++) {
        acc[i][j] = __builtin_amdgcn_mfma_f32_16x16x32_bf16(ah[i], bh[j], acc[i][j], 0, 0, 0);
        acc[i][j] = __builtin_amdgcn_mfma_f32_16x16x32_bf16(ah[i], bl[j], acc[i][j], 0, 0, 0);
        acc[i][j] = __builtin_amdgcn_mfma_f32_16x16x32_bf16(al[i], bh[j], acc[i][j], 0, 0, 0);
      }
    __syncthreads();
  }

  // v epilogue: bias only -> kv fp32 (frees accv)
  int b256 = b * 256;
  #pragma unroll
  for (int i = 0; i < 2; i++) {
    #pragma unroll
    for (int r = 0; r < 4; r++) {
      int row = i * 16 + l4 * 4 + r;  // 0..31
      int cch = h * 32 + row;
      float bias = qkvb[512 + cch];
      #pragma unroll
      for (int j = 0; j < 2; j++) {
        int n = n0 + w * 32 + j * 16 + l15;
        kv[((long long)(b256 + cch)) * 4096 + n] = accv[i][j][r] + bias;
      }
    }
  }

  // q/k epilogue: bias + PE (+FiLM for q), pack, store to swizzled qk tile
  #pragma unroll
  for (int i = 0; i < 4; i++) {
    #pragma unroll
    for (int r = 0; r < 4; r++) {
      int row = i * 16 + l4 * 4 + r;  // 0..63; i<2 -> q, i>=2 -> k
      int cch = h * 32 + (row & 31);
      float bias = qkvb[(row & 32) ? (256 + cch) : cch];
      float mm = 0.f, mb = 0.f;
      if (row < 32) { mm = modm[b256 + cch]; mb = modb[b256 + cch]; }
      #pragma unroll
      for (int j = 0; j < 2; j++) {
        int nl = w * 32 + j * 16 + l15;
        int n = n0 + nl;
        int hh = n >> 6, ww = n & 63;
        float v = acc[i][j][r] + bias;
        if (row < 32) {
          v += peqh[cch * 64 + hh] + peqw[cch * 64 + ww];
          v = v * mm + mb;
        } else {
          v += pekh[cch * 64 + hh] + pekw[cch * 64 + ww];
        }
        unsigned short hi_, lo_;
        split2(v, hi_, lo_);
        int pch = (nl >> 3) ^ (row & 15);  // chunk swizzle (8 u32 = 32B chunks)
        qk[row * 128 + pch * 8 + (nl & 7)] = (unsigned)hi_ | ((unsigned)lo_ << 16);
      }
    }
  }
  __syncthreads();

  // logits partial: q(32 x 128n) . k(32 x 128n)^T; wave w covers n-slice w*32..
  f32x4 acc2[2][2] = {z, z, z, z};
  int chn = w * 4 + l4;
  bf16x8 qh[2], ql[2], kh[2], kl[2];
  #pragma unroll
  for (int i2 = 0; i2 < 2; i2++) {
    int row = i2 * 16 + l15;
    unpack8(qk + row * 128 + ((chn ^ l15) << 3), qh[i2], ql[i2]);
    unpack8(qk + (row + 32) * 128 + ((chn ^ l15) << 3), kh[i2], kl[i2]);
  }
  acc2[0][0] = __builtin_amdgcn_mfma_f32_16x16x32_bf16(qh[0], kh[0], acc2[0][0], 0, 0, 0);
  acc2[0][0] = __builtin_amdgcn_mfma_f32_16x16x32_bf16(qh[0], kl[0], acc2[0][0], 0, 0, 0);
  acc2[0][0] = __builtin_amdgcn_mfma_f32_16x16x32_bf16(ql[0], kh[0], acc2[0][0], 0, 0, 0);
  acc2[0][1] = __builtin_amdgcn_mfma_f32_16x16x32_bf16(qh[0], kh[1], acc2[0][1], 0, 0, 0);
  acc2[0][1] = __builtin_amdgcn_mfma_f32_16x16x32_bf16(qh[0], kl[1], acc2[0][1], 0, 0, 0);
  acc2[0][1] = __builtin_amdgcn_mfma_f32_16x16x32_bf16(ql[0], kh[1], acc2[0][1], 0, 0, 0);
  acc2[1][0] = __builtin_amdgcn_mfma_f32_16x16x32_bf16(qh[1], kh[0], acc2[1][0], 0, 0, 0);
  acc2[1][0] = __builtin_amdgcn_mfma_f32_16x16x32_bf16(qh[1], kl[0], acc2[1][0], 0, 0, 0);
  acc2[1][0] = __builtin_amdgcn_mfma_f32_16x16x32_bf16(ql[1], kh[0], acc2[1][0], 0, 0, 0);
  acc2[1][1] = __builtin_amdgcn_mfma_f32_16x16x32_bf16(qh[1], kh[1], acc2[1][1], 0, 0, 0);
  acc2[1][1] = __builtin_amdgcn_mfma_f32_16x16x32_bf16(qh[1], kl[1], acc2[1][1], 0, 0, 0);
  acc2[1][1] = __builtin_amdgcn_mfma_f32_16x16x32_bf16(ql[1], kh[1], acc2[1][1], 0, 0, 0);

  // red aliases qk: wait for ALL waves' qk reads before overwriting
  __syncthreads();
  #pragma unroll
  for (int i2 = 0; i2 < 2; i2++)
    #pragma unroll
    for (int j2 = 0; j2 < 2; j2++)
      #pragma unroll
      for (int r = 0; r < 4; r++)
        red[w * 1024 + (i2 * 16 + l4 * 4 + r) * 32 + j2 * 16 + l15] = acc2[i2][j2][r];
  __syncthreads();
  const float scale = 0.1767766952966369f;  // 1/sqrt(32)
  int bhid = b * 8 + h;
  #pragma unroll
  for (int i = 0; i < 4; i++) {
    int idx = i * 256 + t;
    float s = (red[idx] + red[1024 + idx] + red[2048 + idx] + red[3072 + idx]) * scale;
    atomicAdd(logits + (long long)bhid * 1024 + idx, s);
  }
}

// K3: softmax (logits already summed by atomics, already scaled) + weights @ v
__global__ __launch_bounds__(256) void k_pv(
    const float* __restrict__ kv,    // v
    const float* __restrict__ logits,
    float* __restrict__ out) {
  int bx = blockIdx.x;
  int ntile = bx & 15, bh = bx >> 4;
  int b = bh >> 3, h = bh & 7;
  int t = threadIdx.x;
  __shared__ float raw[32][33];   // [c][d], padded: serial reads conflict-free
  __shared__ float wsm[32][33];
  #pragma unroll
  for (int i = 0; i < 4; i++) {
    int idx = i * 256 + t;
    raw[idx >> 5][idx & 31] = logits[(long long)bh * 1024 + idx];
  }
  __syncthreads();
  if (t < 32) {
    float mx = -1e30f;
    for (int d = 0; d < 32; d++) mx = fmaxf(mx, raw[t][d]);
    float e[32]; float s = 0.f;
    for (int d = 0; d < 32; d++) { e[d] = __expf(raw[t][d] - mx); s += e[d]; }
    float inv = 1.0f / s;
    for (int d = 0; d < 32; d++) wsm[t][d] = e[d] * inv;
  }
  __syncthreads();
  int rg = t >> 6;          // wave-uniform -> wsm broadcast
  int nl = (t & 63) * 4;
  int n0 = ntile * 256 + nl;
  const float* vb = kv + ((long long)(b * 256 + h * 32)) * 4096 + n0;
  float acc[8][4];
  #pragma unroll
  for (int r = 0; r < 8; r++)
    #pragma unroll
    for (int i = 0; i < 4; i++) acc[r][i] = 0.f;
  for (int d = 0; d < 32; d++) {
    float4 vv = *(const float4*)(vb + (long long)d * 4096);
    #pragma unroll
    for (int r = 0; r < 8; r++) {
      float wv = wsm[rg * 8 + r][d];
      acc[r][0] += wv * vv.x; acc[r][1] += wv * vv.y;
      acc[r][2] += wv * vv.z; acc[r][3] += wv * vv.w;
    }
  }
  #pragma unroll
  for (int r = 0; r < 8; r++) {
    long long oidx = ((long long)(b * 512 + 256 + h * 32 + rg * 8 + r)) * 4096 + n0;
    float4 ov = {acc[r][0], acc[r][1], acc[r][2], acc[r][3]};
    *(float4*)(out + oidx) = ov;
  }
}

extern "C" void kernel_launch(void* const* d_in, const int* in_sizes, int n_in,
                              void* d_out, int out_size, void* d_ws, size_t ws_size,
                              hipStream_t stream) {
  const float* x    = (const float*)d_in[0];
  const float* modm = (const float*)d_in[1];
  const float* modb = (const float*)d_in[2];
  const float* Wq   = (const float*)d_in[3];
  const float* qkvb = (const float*)d_in[4];
  const float* peqh = (const float*)d_in[5];
  const float* peqw = (const float*)d_in[6];
  const float* pekh = (const float*)d_in[7];
  const float* pekw = (const float*)d_in[8];
  const float* pab  = (const float*)d_in[9];
  const float* pqb  = (const float*)d_in[10];
  float* out = (float*)d_out;

  // ws layout (67 MB total, <= 69.2 MB proven):
  //   [0, 0.75MB)    Wh/Wl u16[768][256] split-bf16 planes
  //   [1MB, 1.5MB)   logits f32[16][8][32][32] (atomic-accumulated, pre-scaled)
  //   [3MB, 67MB)    v fp32 [16][256][4096]
  unsigned short* Wh = (unsigned short*)d_ws;
  unsigned short* Wl = Wh + 768 * 256;
  float* logits = (float*)((char*)d_ws + (1 << 20));
  float* kv = (float*)((char*)d_ws + 3 * (1 << 20));

  hipMemsetAsync(logits, 0, 524288, stream);
  k_prep<<<4192, 256, 0, stream>>>(x, pab, pqb, Wq, Wh, Wl, out);
  k_qkl<<<4096, 256, 0, stream>>>(Wh, Wl, qkvb, peqh, peqw, pekh, pekw,
                                  modm, modb, out, kv, logits);
  k_pv<<<2048, 256, 0, stream>>>(kv, logits, out);
}